// Round 11
// baseline (511.538 us; speedup 1.0000x reference)
//
#include <hip/hip_runtime.h>
#include <math.h>

// Every rounding is deliberate: bit-match the reference fp32 pipeline
// (ascending single-accumulator FMA dot — verified rounds 4-10, absmax=0).
#pragma clang fp contract(off)

typedef __attribute__((ext_vector_type(2))) float f2;

constexpr int KCODES = 2048;   // EMBEDDING_LENGTH
constexpr int CDIM   = 4;      // EMBEDDING_DIM
constexpr int KSPLIT = 8;      // one k-chunk per wave
constexpr int KCHUNK = KCODES / KSPLIT;  // 256 codes per wave
constexpr int NUNITS = KCODES / 2;       // 1024 two-code units

__device__ __forceinline__ f2 pk_mul(f2 a, f2 b) {
    f2 d; asm("v_pk_mul_f32 %0, %1, %2" : "=v"(d) : "v"(a), "v"(b)); return d;
}
__device__ __forceinline__ f2 pk_fma(f2 a, f2 b, f2 c) {
    f2 d; asm("v_pk_fma_f32 %0, %1, %2, %3" : "=v"(d) : "v"(a), "v"(b), "v"(c)); return d;
}
__device__ __forceinline__ f2 pk_add(f2 a, f2 b) {
    f2 d; asm("v_pk_add_f32 %0, %1, %2" : "=v"(d) : "v"(a), "v"(b)); return d;
}
__device__ __forceinline__ float min3f(float a, float b, float c) {
    float d; asm("v_min3_f32 %0, %1, %2, %3" : "=v"(d) : "v"(a), "v"(b), "v"(c)); return d;
}
__device__ __forceinline__ float sumsq(float4 e) {
    return ((e.x * e.x + e.y * e.y) + e.z * e.z) + e.w * e.w;
}

// One template, four instances:
//   <4,true,1>  -> d_out producer, structurally identical to round 10 (known-good)
//   <4,true,8>  -> P1: full pipeline x8 (visibility + calibration)
//   <4,false,8> -> P2: scan-only x8 (resolution ablated)
//   <1,false,8> -> P3: scan-only x8 at r9 geometry (occupancy/per-wave-path probe)
template <int RPT, bool RESOLVE, int REP>
__global__ __launch_bounds__(512) void vq_kern(
    const float* __restrict__ x,
    const float* __restrict__ emb,
    int* __restrict__ out,
    unsigned long long* __restrict__ sink,
    int N)
{
    __shared__ float4 sEP[NUNITS * 2];   // 32 KB transposed pairs
    __shared__ float4 sSP[KCODES / 4];   //  8 KB packed sums

    const float4* __restrict__ embf4 = reinterpret_cast<const float4*>(emb);
    const int t = threadIdx.x;

    for (int j = t; j < NUNITS; j += 512) {
        float4 a = embf4[2 * j], b = embf4[2 * j + 1];
        sEP[2 * j]     = make_float4(a.x, b.x, a.y, b.y);
        sEP[2 * j + 1] = make_float4(a.z, b.z, a.w, b.w);
    }
    for (int q = t; q < KCODES / 4; q += 512) {
        float4 e0 = embf4[4 * q],     e1 = embf4[4 * q + 1];
        float4 e2 = embf4[4 * q + 2], e3 = embf4[4 * q + 3];
        sSP[q] = make_float4(sumsq(e0), sumsq(e1), sumsq(e2), sumsq(e3));
    }
    __syncthreads();

    const int lane = t & 63;
    const int wid   = __builtin_amdgcn_readfirstlane(t >> 6);
    const int kbase = wid * KCHUNK;
    const int ubase = kbase >> 1;
    const int qbase = kbase >> 2;
    const int ROWSPB = 64 * RPT;
    const int nbase = blockIdx.x * ROWSPB + lane;

    float4 xv[RPT];
    f2 xx[RPT], yy[RPT], zz[RPT], ww[RPT], x2p[RPT];
    #pragma unroll
    for (int r = 0; r < RPT; ++r) {
        const int n = nbase + r * 64;
        xv[r] = (n < N) ? reinterpret_cast<const float4*>(x)[n]
                        : make_float4(0.f, 0.f, 0.f, 0.f);
        const float x2 = ((xv[r].x * xv[r].x + xv[r].y * xv[r].y)
                          + xv[r].z * xv[r].z) + xv[r].w * xv[r].w;
        xx[r] = f2{xv[r].x, xv[r].x}; yy[r] = f2{xv[r].y, xv[r].y};
        zz[r] = f2{xv[r].z, xv[r].z}; ww[r] = f2{xv[r].w, xv[r].w};
        x2p[r] = f2{x2, x2};
    }
    const f2 m2 = {-2.0f, -2.0f};

    unsigned long long key[RPT];
    unsigned long long acc = 0;

    for (int rep = 0; rep < REP; ++rep) {
        float dmin[RPT];
        int   bg[RPT];
        #pragma unroll
        for (int r = 0; r < RPT; ++r) {
            // Anti-CSE perturbation (rule #17): declare scan inputs modified
            // so the compiler cannot hoist/merge rep iterations. No-op at HW.
            asm volatile("" : "+v"(xx[r]), "+v"(yy[r]), "+v"(zz[r]),
                              "+v"(ww[r]), "+v"(x2p[r]));
            dmin[r] = HUGE_VALF; bg[r] = 0;
        }

        for (int g = 0; g < KCHUNK / 8; ++g) {   // 32 groups x 8 codes
            float prev[RPT];
            #pragma unroll
            for (int r = 0; r < RPT; ++r) prev[r] = dmin[r];

            const float4 sA = sSP[qbase + 2 * g];
            const float4 sB = sSP[qbase + 2 * g + 1];
            const int u0 = ubase + 4 * g;
            #pragma unroll
            for (int uu = 0; uu < 4; ++uu) {
                const float4 qa = sEP[2 * (u0 + uu)];
                const float4 qb = sEP[2 * (u0 + uu) + 1];
                const f2 ea = {qa.x, qa.y}, eb = {qa.z, qa.w};
                const f2 ec = {qb.x, qb.y}, ed = {qb.z, qb.w};
                const f2 sp = (uu == 0) ? f2{sA.x, sA.y} :
                              (uu == 1) ? f2{sA.z, sA.w} :
                              (uu == 2) ? f2{sB.x, sB.y} : f2{sB.z, sB.w};
                #pragma unroll
                for (int r = 0; r < RPT; ++r) {
                    f2 dot = pk_mul(xx[r], ea);
                    dot = pk_fma(yy[r], eb, dot);
                    dot = pk_fma(zz[r], ec, dot);
                    dot = pk_fma(ww[r], ed, dot);
                    f2 dd = pk_add(pk_fma(m2, dot, x2p[r]), sp);
                    dmin[r] = min3f(dmin[r], dd.x, dd.y);
                }
            }
            #pragma unroll
            for (int r = 0; r < RPT; ++r)
                if (dmin[r] < prev[r]) bg[r] = g;
        }

        #pragma unroll
        for (int r = 0; r < RPT; ++r) {
            if constexpr (RESOLVE) {
                const int k0 = kbase + (bg[r] << 3);
                int idx = 0x7fffffff;
                #pragma unroll
                for (int q = 0; q < 8; ++q) {
                    const int k = k0 + q;
                    const float4 e = embf4[k];
                    const float s = sumsq(e);
                    float dot = xv[r].x * e.x;
                    dot = __builtin_fmaf(xv[r].y, e.y, dot);
                    dot = __builtin_fmaf(xv[r].z, e.z, dot);
                    dot = __builtin_fmaf(xv[r].w, e.w, dot);
                    const float d = __builtin_fmaf(-2.0f, dot, x2p[r].x) + s;
                    idx = min(idx, (d == dmin[r]) ? k : 0x7fffffff);
                }
                key[r] = ((unsigned long long)__float_as_uint(dmin[r]) << 32)
                         | (unsigned)idx;
            } else {
                key[r] = ((unsigned long long)__float_as_uint(dmin[r]) << 32)
                         | (unsigned)bg[r];
            }
            acc ^= key[r] + (unsigned long long)rep;
        }
    }

    if constexpr (REP == 1 && RESOLVE) {
        // ---- known-good r10 tail: cross-wave reduce -> out ----
        __syncthreads();
        unsigned long long* skey = reinterpret_cast<unsigned long long*>(sEP);
        #pragma unroll
        for (int r = 0; r < RPT; ++r)
            skey[(r * 64 + lane) * (KSPLIT + 1) + wid] = key[r];
        __syncthreads();

        if (t < ROWSPB) {
            const int rn = blockIdx.x * ROWSPB + t;
            if (rn < N) {
                unsigned long long k = skey[t * (KSPLIT + 1)];
                #pragma unroll
                for (int s = 1; s < KSPLIT; ++s) {
                    unsigned long long v = skey[t * (KSPLIT + 1) + s];
                    if (v < k) k = v;
                }
                out[rn] = (int)(unsigned)(k & 0xFFFFFFFFull);
            }
        }
    } else {
        // probe: keep all reps live, write to scratch
        sink[(size_t)blockIdx.x * 512 + t] = acc;
    }
}

extern "C" void kernel_launch(void* const* d_in, const int* in_sizes, int n_in,
                              void* d_out, int out_size, void* d_ws, size_t ws_size,
                              hipStream_t stream) {
    const float* x   = (const float*)d_in[0];   // [16,64,64,4] -> [N,4]
    const float* emb = (const float*)d_in[1];   // [2048,4]
    int* out = (int*)d_out;                     // [N] int32
    const int N = in_sizes[0] / CDIM;           // 65536

    unsigned long long* ws64 = (unsigned long long*)d_ws;

    // d_out producer: unchanged round-10 structure (known good).
    vq_kern<4, true, 1><<<256, 512, 0, stream>>>(x, emb, out, ws64, N);

    // Diagnostic probes (counters + within-probe A/B/C). Scratch-only writes;
    // deterministic; skipped if workspace is small.
    if (ws_size >= (size_t)32 << 20) {
        unsigned long long* s1 = (unsigned long long*)((char*)d_ws + (4u << 20));
        unsigned long long* s2 = (unsigned long long*)((char*)d_ws + (12u << 20));
        unsigned long long* s3 = (unsigned long long*)((char*)d_ws + (20u << 20));
        vq_kern<4, true,  8><<<256,  512, 0, stream>>>(x, emb, out, s1, N);  // P1
        vq_kern<4, false, 8><<<256,  512, 0, stream>>>(x, emb, out, s2, N);  // P2
        vq_kern<1, false, 8><<<1024, 512, 0, stream>>>(x, emb, out, s3, N);  // P3
    }
}

// Round 12
// 372.624 us; speedup vs baseline: 1.3728x; 1.3728x over previous
//
#include <hip/hip_runtime.h>
#include <math.h>

// Every rounding is deliberate: bit-match the reference fp32 pipeline
// (ascending single-accumulator FMA dot — verified rounds 4-11, absmax=0).
#pragma clang fp contract(off)

typedef __attribute__((ext_vector_type(2))) float f2;

constexpr int KCODES = 2048;   // EMBEDDING_LENGTH
constexpr int CDIM   = 4;      // EMBEDDING_DIM
constexpr int KSPLIT = 8;      // one k-chunk per wave
constexpr int KCHUNK = KCODES / KSPLIT;  // 256 codes per wave
constexpr int RPT    = 4;      // rows per lane
constexpr int ROWSPB = 64 * RPT;         // 256 rows per block
constexpr int NUNITS = KCODES / 2;       // 1024 two-code units

__device__ __forceinline__ f2 pk_mul(f2 a, f2 b) {
    f2 d; asm("v_pk_mul_f32 %0, %1, %2" : "=v"(d) : "v"(a), "v"(b)); return d;
}
__device__ __forceinline__ f2 pk_fma(f2 a, f2 b, f2 c) {
    f2 d; asm("v_pk_fma_f32 %0, %1, %2, %3" : "=v"(d) : "v"(a), "v"(b), "v"(c)); return d;
}
__device__ __forceinline__ f2 pk_add(f2 a, f2 b) {
    f2 d; asm("v_pk_add_f32 %0, %1, %2" : "=v"(d) : "v"(a), "v"(b)); return d;
}
__device__ __forceinline__ float min3f(float a, float b, float c) {
    float d; asm("v_min3_f32 %0, %1, %2, %3" : "=v"(d) : "v"(a), "v"(b), "v"(c)); return d;
}
__device__ __forceinline__ float sumsq(float4 e) {
    return ((e.x * e.x + e.y * e.y) + e.z * e.z) + e.w * e.w;
}

// Scan tracks (dmin, winning UNIT=pair) — resolution needs NO global scatter:
// recompute one pair per row from LDS (bit-identical scalar chain).
//   <1,false> -> d_out producer
//   <16,true> -> probe x16 to scratch (the ONLY probe: top-5 visibility)
template <int REP, bool SINK>
__global__ __launch_bounds__(512) void vq_kern(
    const float* __restrict__ x,
    const float* __restrict__ emb,
    int* __restrict__ out,
    unsigned long long* __restrict__ sink,
    int N)
{
    __shared__ float4 sEP[NUNITS * 2];   // 32 KB: {e0a,e0b,e1a,e1b}{e2a,e2b,e3a,e3b}
    __shared__ float4 sSP[KCODES / 4];   //  8 KB: s packed 4/quad

    const float4* __restrict__ embf4 = reinterpret_cast<const float4*>(emb);
    const int t = threadIdx.x;

    for (int j = t; j < NUNITS; j += 512) {
        float4 a = embf4[2 * j], b = embf4[2 * j + 1];
        sEP[2 * j]     = make_float4(a.x, b.x, a.y, b.y);
        sEP[2 * j + 1] = make_float4(a.z, b.z, a.w, b.w);
    }
    for (int q = t; q < KCODES / 4; q += 512) {
        float4 e0 = embf4[4 * q],     e1 = embf4[4 * q + 1];
        float4 e2 = embf4[4 * q + 2], e3 = embf4[4 * q + 3];
        sSP[q] = make_float4(sumsq(e0), sumsq(e1), sumsq(e2), sumsq(e3));
    }
    __syncthreads();

    const int lane = t & 63;
    const int wid   = __builtin_amdgcn_readfirstlane(t >> 6);  // r6 lesson
    const int kbase = wid * KCHUNK;
    const int ubase = kbase >> 1;
    const int qbase = kbase >> 2;
    const int nbase = blockIdx.x * ROWSPB + lane;

    float4 xv[RPT];
    f2 xx[RPT], yy[RPT], zz[RPT], ww[RPT], x2p[RPT];
    #pragma unroll
    for (int r = 0; r < RPT; ++r) {
        const int n = nbase + r * 64;
        xv[r] = (n < N) ? reinterpret_cast<const float4*>(x)[n]
                        : make_float4(0.f, 0.f, 0.f, 0.f);
        const float x2 = ((xv[r].x * xv[r].x + xv[r].y * xv[r].y)
                          + xv[r].z * xv[r].z) + xv[r].w * xv[r].w;
        xx[r] = f2{xv[r].x, xv[r].x}; yy[r] = f2{xv[r].y, xv[r].y};
        zz[r] = f2{xv[r].z, xv[r].z}; ww[r] = f2{xv[r].w, xv[r].w};
        x2p[r] = f2{x2, x2};
    }
    const f2 m2 = {-2.0f, -2.0f};

    unsigned long long key[RPT];
    unsigned long long acc = 0;

    for (int rep = 0; rep < REP; ++rep) {
        float dmin[RPT];
        int   bu[RPT];     // winning unit (pair) index, absolute
        #pragma unroll
        for (int r = 0; r < RPT; ++r) {
            if constexpr (REP > 1)   // anti-CSE across reps (no-op at HW)
                asm volatile("" : "+v"(xx[r]), "+v"(yy[r]), "+v"(zz[r]),
                                  "+v"(ww[r]), "+v"(x2p[r]));
            dmin[r] = HUGE_VALF; bu[r] = ubase;
        }

        for (int g = 0; g < KCHUNK / 8; ++g) {   // 32 groups x 4 pairs
            const float4 sA = sSP[qbase + 2 * g];
            const float4 sB = sSP[qbase + 2 * g + 1];
            const int u0 = ubase + 4 * g;
            #pragma unroll
            for (int uu = 0; uu < 4; ++uu) {
                const float4 qa = sEP[2 * (u0 + uu)];
                const float4 qb = sEP[2 * (u0 + uu) + 1];
                const f2 ea = {qa.x, qa.y}, eb = {qa.z, qa.w};
                const f2 ec = {qb.x, qb.y}, ed = {qb.z, qb.w};
                const f2 sp = (uu == 0) ? f2{sA.x, sA.y} :
                              (uu == 1) ? f2{sA.z, sA.w} :
                              (uu == 2) ? f2{sB.x, sB.y} : f2{sB.z, sB.w};
                #pragma unroll
                for (int r = 0; r < RPT; ++r) {
                    f2 dot = pk_mul(xx[r], ea);
                    dot = pk_fma(yy[r], eb, dot);
                    dot = pk_fma(zz[r], ec, dot);
                    dot = pk_fma(ww[r], ed, dot);
                    f2 dd = pk_add(pk_fma(m2, dot, x2p[r]), sp);
                    // track winning pair: strict < keeps earliest on ties
                    float nd = min3f(dmin[r], dd.x, dd.y);
                    if (nd < dmin[r]) bu[r] = u0 + uu;   // cmp + cndmask
                    dmin[r] = nd;                         // SSA: no copy
                }
            }
        }

        // ---- resolution: recompute ONE pair per row from LDS (bit-identical
        // scalar chain == pk halves), pick even code first on exact ties.
        const float2* __restrict__ sSPf2 = reinterpret_cast<const float2*>(sSP);
        #pragma unroll
        for (int r = 0; r < RPT; ++r) {
            const int u = bu[r];
            const float4 qa = sEP[2 * u];        // divergent ds_read (tiny)
            const float4 qb = sEP[2 * u + 1];
            const float2 sv = sSPf2[u];
            // even code e = (qa.x, qa.z, qb.x, qb.z), s = sv.x
            float dot = xv[r].x * qa.x;
            dot = __builtin_fmaf(xv[r].y, qa.z, dot);
            dot = __builtin_fmaf(xv[r].z, qb.x, dot);
            dot = __builtin_fmaf(xv[r].w, qb.z, dot);
            const float de = __builtin_fmaf(-2.0f, dot, x2p[r].x) + sv.x;
            const int idx = 2 * u + ((de == dmin[r]) ? 0 : 1);
            // d >= 0: float bits order-isomorphic as u32; low bits break
            // exact cross-wave ties toward the smaller index.
            key[r] = ((unsigned long long)__float_as_uint(dmin[r]) << 32)
                     | (unsigned)idx;
            if constexpr (SINK) acc ^= key[r] + (unsigned long long)rep;
        }
    }

    if constexpr (!SINK) {
        // ---- known-good r10 tail: cross-wave reduce -> out ----
        __syncthreads();
        unsigned long long* skey = reinterpret_cast<unsigned long long*>(sEP);
        #pragma unroll
        for (int r = 0; r < RPT; ++r)
            skey[(r * 64 + lane) * (KSPLIT + 1) + wid] = key[r];
        __syncthreads();

        if (t < ROWSPB) {
            const int rn = blockIdx.x * ROWSPB + t;
            if (rn < N) {
                unsigned long long k = skey[t * (KSPLIT + 1)];
                #pragma unroll
                for (int s = 1; s < KSPLIT; ++s) {
                    unsigned long long v = skey[t * (KSPLIT + 1) + s];
                    if (v < k) k = v;
                }
                out[rn] = (int)(unsigned)(k & 0xFFFFFFFFull);
            }
        }
    } else {
        sink[(size_t)blockIdx.x * 512 + t] = acc;
    }
}

extern "C" void kernel_launch(void* const* d_in, const int* in_sizes, int n_in,
                              void* d_out, int out_size, void* d_ws, size_t ws_size,
                              hipStream_t stream) {
    const float* x   = (const float*)d_in[0];   // [16,64,64,4] -> [N,4]
    const float* emb = (const float*)d_in[1];   // [2048,4]
    int* out = (int*)d_out;                     // [N] int32
    const int N = in_sizes[0] / CDIM;           // 65536

    unsigned long long* ws64 = (unsigned long long*)d_ws;

    // d_out producer (zero-memory-resolve scan)
    vq_kern<1, false><<<(N + ROWSPB - 1) / ROWSPB, 512, 0, stream>>>(
        x, emb, out, ws64, N);

    // ONE probe: full pipeline x16 -> guaranteed slowest dispatch, clean
    // counters. Writes scratch only.
    if (ws_size >= (size_t)4 << 20) {
        unsigned long long* s1 =
            (unsigned long long*)((char*)d_ws + (1u << 20));
        vq_kern<16, true><<<(N + ROWSPB - 1) / ROWSPB, 512, 0, stream>>>(
            x, emb, out, s1, N);
    }
}

// Round 13
// 28.285 us; speedup vs baseline: 18.0851x; 13.1739x over previous
//
#include <hip/hip_runtime.h>
#include <math.h>

// Every rounding is deliberate: bit-match the reference fp32 pipeline
// (ascending single-accumulator FMA dot — verified rounds 4-12, absmax=0).
// contract(off) blocks AUTOMATIC fusion; explicit fma builtins are kept.
#pragma clang fp contract(off)

typedef __attribute__((ext_vector_type(2))) float f2;

constexpr int KCODES = 2048;   // EMBEDDING_LENGTH
constexpr int CDIM   = 4;      // EMBEDDING_DIM
constexpr int KSPLIT = 8;      // one k-chunk per wave
constexpr int KCHUNK = KCODES / KSPLIT;  // 256 codes per wave
constexpr int RPT    = 2;      // rows per lane: 2 blocks/CU = 4 waves/SIMD
constexpr int ROWSPB = 64 * RPT;         // 128 rows per block
constexpr int NUNITS = KCODES / 2;       // 1024 two-code units

__device__ __forceinline__ float min3f(float a, float b, float c) {
    float d; asm("v_min3_f32 %0, %1, %2, %3" : "=v"(d) : "v"(a), "v"(b), "v"(c)); return d;
}
__device__ __forceinline__ float sumsq(float4 e) {
    // np.sum(e*e, -1): ascending unfused mul-add (n<8 scalar loop)
    return ((e.x * e.x + e.y * e.y) + e.z * e.z) + e.w * e.w;
}

// Scan tracks (dmin, winning pair); resolution recomputes ONE pair per row
// from LDS with the bit-identical scalar chain (r12 structure, absmax=0).
// Packed math via native <2 x float> ops / __builtin_elementwise_fma:
// each half is IEEE-RNE identical to scalar; backend emits v_pk_* with free
// register allocation (no inline-asm constraint movs — r12 suspect #2).
__global__ __launch_bounds__(512) void vq_fused(
    const float* __restrict__ x,
    const float* __restrict__ emb,
    int* __restrict__ out,
    int N)
{
    __shared__ float4 sEP[NUNITS * 2];   // 32 KB: {e0a,e0b,e1a,e1b}{e2a,e2b,e3a,e3b}
    __shared__ float4 sSP[KCODES / 4];   //  8 KB: s packed 4/quad

    const float4* __restrict__ embf4 = reinterpret_cast<const float4*>(emb);
    const int t = threadIdx.x;

    for (int j = t; j < NUNITS; j += 512) {
        float4 a = embf4[2 * j], b = embf4[2 * j + 1];
        sEP[2 * j]     = make_float4(a.x, b.x, a.y, b.y);
        sEP[2 * j + 1] = make_float4(a.z, b.z, a.w, b.w);
    }
    for (int q = t; q < KCODES / 4; q += 512) {
        float4 e0 = embf4[4 * q],     e1 = embf4[4 * q + 1];
        float4 e2 = embf4[4 * q + 2], e3 = embf4[4 * q + 3];
        sSP[q] = make_float4(sumsq(e0), sumsq(e1), sumsq(e2), sumsq(e3));
    }
    __syncthreads();

    const int lane = t & 63;
    const int wid   = __builtin_amdgcn_readfirstlane(t >> 6);  // r6 lesson
    const int kbase = wid * KCHUNK;
    const int ubase = kbase >> 1;
    const int qbase = kbase >> 2;
    const int nbase = blockIdx.x * ROWSPB + lane;

    float4 xv[RPT];
    f2 xx[RPT], yy[RPT], zz[RPT], ww[RPT], x2p[RPT];
    float dmin[RPT];
    int   bu[RPT];
    #pragma unroll
    for (int r = 0; r < RPT; ++r) {
        const int n = nbase + r * 64;
        xv[r] = (n < N) ? reinterpret_cast<const float4*>(x)[n]
                        : make_float4(0.f, 0.f, 0.f, 0.f);
        const float x2 = ((xv[r].x * xv[r].x + xv[r].y * xv[r].y)
                          + xv[r].z * xv[r].z) + xv[r].w * xv[r].w;
        xx[r] = f2{xv[r].x, xv[r].x}; yy[r] = f2{xv[r].y, xv[r].y};
        zz[r] = f2{xv[r].z, xv[r].z}; ww[r] = f2{xv[r].w, xv[r].w};
        x2p[r] = f2{x2, x2};
        dmin[r] = HUGE_VALF; bu[r] = ubase;
    }
    const f2 m2 = {-2.0f, -2.0f};

    for (int g = 0; g < KCHUNK / 8; ++g) {   // 32 groups x 4 pairs
        const float4 sA = sSP[qbase + 2 * g];
        const float4 sB = sSP[qbase + 2 * g + 1];
        const int u0 = ubase + 4 * g;
        #pragma unroll
        for (int uu = 0; uu < 4; ++uu) {
            const float4 qa = sEP[2 * (u0 + uu)];
            const float4 qb = sEP[2 * (u0 + uu) + 1];
            const f2 ea = {qa.x, qa.y}, eb = {qa.z, qa.w};
            const f2 ec = {qb.x, qb.y}, ed = {qb.z, qb.w};
            const f2 sp = (uu == 0) ? f2{sA.x, sA.y} :
                          (uu == 1) ? f2{sA.z, sA.w} :
                          (uu == 2) ? f2{sB.x, sB.y} : f2{sB.z, sB.w};
            #pragma unroll
            for (int r = 0; r < RPT; ++r) {
                // ascending FMA chain, 2 codes at once; each half IEEE-RNE,
                // bitwise == the verified scalar reference pipeline.
                f2 dot = xx[r] * ea;                          // v_pk_mul_f32
                dot = __builtin_elementwise_fma(yy[r], eb, dot);
                dot = __builtin_elementwise_fma(zz[r], ec, dot);
                dot = __builtin_elementwise_fma(ww[r], ed, dot);
                f2 dd = __builtin_elementwise_fma(m2, dot, x2p[r]) + sp;
                float nd = min3f(dmin[r], dd.x, dd.y);        // exact min
                bu[r] = (nd < dmin[r]) ? (u0 + uu) : bu[r];   // earliest ties
                dmin[r] = nd;
            }
        }
    }

    // ---- resolution: recompute ONE pair per row from LDS (bit-identical
    // scalar chain == packed halves); even code wins exact ties -> first occ.
    const float2* __restrict__ sSPf2 = reinterpret_cast<const float2*>(sSP);
    unsigned long long key[RPT];
    #pragma unroll
    for (int r = 0; r < RPT; ++r) {
        const int u = bu[r];
        const float4 qa = sEP[2 * u];        // divergent ds_read (3 per row)
        const float4 qb = sEP[2 * u + 1];
        const float2 sv = sSPf2[u];
        float dot = xv[r].x * qa.x;
        dot = __builtin_fmaf(xv[r].y, qa.z, dot);
        dot = __builtin_fmaf(xv[r].z, qb.x, dot);
        dot = __builtin_fmaf(xv[r].w, qb.z, dot);
        const float de = __builtin_fmaf(-2.0f, dot, x2p[r].x) + sv.x;
        const int idx = 2 * u + ((de == dmin[r]) ? 0 : 1);
        // d >= 0: float bits order-isomorphic as u32; low bits break exact
        // cross-wave ties toward the smaller index (np.argmin semantics).
        key[r] = ((unsigned long long)__float_as_uint(dmin[r]) << 32)
                 | (unsigned)idx;
    }

    // ---- cross-wave reduce: reuse sEP's LDS (stride 9 u64 -> 2-way = free) --
    __syncthreads();
    unsigned long long* skey = reinterpret_cast<unsigned long long*>(sEP);
    #pragma unroll
    for (int r = 0; r < RPT; ++r)
        skey[(r * 64 + lane) * (KSPLIT + 1) + wid] = key[r];
    __syncthreads();

    if (t < ROWSPB) {
        const int rn = blockIdx.x * ROWSPB + t;
        if (rn < N) {
            unsigned long long k = skey[t * (KSPLIT + 1)];
            #pragma unroll
            for (int s = 1; s < KSPLIT; ++s) {
                unsigned long long v = skey[t * (KSPLIT + 1) + s];
                if (v < k) k = v;
            }
            out[rn] = (int)(unsigned)(k & 0xFFFFFFFFull);
        }
    }
}

extern "C" void kernel_launch(void* const* d_in, const int* in_sizes, int n_in,
                              void* d_out, int out_size, void* d_ws, size_t ws_size,
                              hipStream_t stream) {
    const float* x   = (const float*)d_in[0];   // [16,64,64,4] -> [N,4]
    const float* emb = (const float*)d_in[1];   // [2048,4]
    int* out = (int*)d_out;                     // [N] int32
    const int N = in_sizes[0] / CDIM;           // 65536

    vq_fused<<<(N + ROWSPB - 1) / ROWSPB, 512, 0, stream>>>(x, emb, out, N);
}

// Round 14
// 28.175 us; speedup vs baseline: 18.1558x; 1.0039x over previous
//
#include <hip/hip_runtime.h>
#include <math.h>

// Bit-match the verified reference fp32 pipeline (rounds 4-13, absmax=0):
//   dot = ascending single-accumulator FMA chain
//   d   = (x2 - 2*dot) + e2, single roundings, strict-< first-occurrence argmin.
// This version folds -2 into the staged table: e' = -2e (exact). Since RNE
// commutes with exact scaling by 2 and negation, the chain
//   dot' = fma(x3,e'3, fma(x2,e'2, fma(x1,e'1, x0*e'0))) == -2*dot bitwise
// and tmp = x2 + dot' == fmaf(-2,dot,x2) == reference. Scalar-only hot loop:
// no vector types -> no pack/unpack/constraint movs (r12/r13's 2.4x VALU bloat).
#pragma clang fp contract(off)

constexpr int KCODES = 2048;   // EMBEDDING_LENGTH
constexpr int CDIM   = 4;      // EMBEDDING_DIM
constexpr int KSPLIT = 8;      // one k-chunk per wave
constexpr int KCHUNK = KCODES / KSPLIT;  // 256 codes per wave
constexpr int RPT    = 2;      // rows per lane: 2 blocks/CU = 4 waves/SIMD
constexpr int ROWSPB = 64 * RPT;         // 128 rows per block

__device__ __forceinline__ float min3f(float a, float b, float c) {
    float d; asm("v_min3_f32 %0, %1, %2, %3" : "=v"(d) : "v"(a), "v"(b), "v"(c)); return d;
}
__device__ __forceinline__ float sumsq(float4 e) {
    // np.sum(e*e, -1): ascending unfused mul-add (n<8 scalar loop)
    return ((e.x * e.x + e.y * e.y) + e.z * e.z) + e.w * e.w;
}

__global__ __launch_bounds__(512, 4) void vq_fused(
    const float* __restrict__ x,
    const float* __restrict__ emb,
    int* __restrict__ out,
    int N)
{
    __shared__ float4 sE[KCODES];       // 32 KB: e' = -2e per code
    __shared__ float4 sS[KCODES / 4];   //  8 KB: e2 sums, 4 codes per float4

    const float4* __restrict__ embf4 = reinterpret_cast<const float4*>(emb);
    const int t = threadIdx.x;

    for (int i = t; i < KCODES; i += 512) {
        float4 e = embf4[i];
        sE[i] = make_float4(-2.0f * e.x, -2.0f * e.y, -2.0f * e.z, -2.0f * e.w);
    }
    for (int q = t; q < KCODES / 4; q += 512) {
        float4 e0 = embf4[4 * q],     e1 = embf4[4 * q + 1];
        float4 e2 = embf4[4 * q + 2], e3 = embf4[4 * q + 3];
        sS[q] = make_float4(sumsq(e0), sumsq(e1), sumsq(e2), sumsq(e3));
    }
    __syncthreads();

    const int lane = t & 63;
    const int wid   = __builtin_amdgcn_readfirstlane(t >> 6);  // r6 lesson
    const int kbase = wid * KCHUNK;
    const int qbase = kbase >> 2;
    const int nbase = blockIdx.x * ROWSPB + lane;

    float x0[RPT], x1[RPT], x2c[RPT], x3[RPT], xs[RPT];
    float dmin[RPT];
    int   bg[RPT];
    #pragma unroll
    for (int r = 0; r < RPT; ++r) {
        const int n = nbase + r * 64;
        float4 xv = (n < N) ? reinterpret_cast<const float4*>(x)[n]
                            : make_float4(0.f, 0.f, 0.f, 0.f);
        x0[r] = xv.x; x1[r] = xv.y; x2c[r] = xv.z; x3[r] = xv.w;
        xs[r] = ((xv.x * xv.x + xv.y * xv.y) + xv.z * xv.z) + xv.w * xv.w;
        dmin[r] = HUGE_VALF; bg[r] = 0;
    }

    // 6 scalar VALU per code:  mul, fma, fma, fma, add(xs), add(s)
    // + 1 min3 per 2 codes + 2 tracking ops per 8-code group.
    #pragma unroll 2
    for (int g = 0; g < KCHUNK / 8; ++g) {   // 32 groups x 8 codes
        const int k0 = kbase + (g << 3);
        const float4 e0 = sE[k0 + 0], e1 = sE[k0 + 1];
        const float4 e2 = sE[k0 + 2], e3 = sE[k0 + 3];
        const float4 e4 = sE[k0 + 4], e5 = sE[k0 + 5];
        const float4 e6 = sE[k0 + 6], e7 = sE[k0 + 7];
        const float4 sA = sS[qbase + 2 * g];
        const float4 sB = sS[qbase + 2 * g + 1];

        #pragma unroll
        for (int r = 0; r < RPT; ++r) {
            const float a0 = x0[r], a1 = x1[r], a2 = x2c[r], a3 = x3[r];
            const float xq = xs[r];
            const float prev = dmin[r];

            #define VQ_D(EV, SV, OUTV)                                   \
                do {                                                     \
                    float dt = a0 * EV.x;                                \
                    dt = __builtin_fmaf(a1, EV.y, dt);                   \
                    dt = __builtin_fmaf(a2, EV.z, dt);                   \
                    dt = __builtin_fmaf(a3, EV.w, dt);                   \
                    OUTV = (xq + dt) + SV;                               \
                } while (0)

            float d0, d1, d2, d3, d4, d5, d6, d7;
            VQ_D(e0, sA.x, d0); VQ_D(e1, sA.y, d1);
            VQ_D(e2, sA.z, d2); VQ_D(e3, sA.w, d3);
            VQ_D(e4, sB.x, d4); VQ_D(e5, sB.y, d5);
            VQ_D(e6, sB.z, d6); VQ_D(e7, sB.w, d7);
            #undef VQ_D

            float m = min3f(dmin[r], d0, d1);
            m = min3f(m, d2, d3);
            m = min3f(m, d4, d5);
            m = min3f(m, d6, d7);
            bg[r] = (m < prev) ? g : bg[r];   // strict <: earliest group ties
            dmin[r] = m;
        }
    }

    // ---- resolution: recompute the 8 winning codes per row from LDS with
    // the identical scalar chain; first bitwise match wins (np.argmin).
    unsigned long long key[RPT];
    #pragma unroll
    for (int r = 0; r < RPT; ++r) {
        const int k0 = kbase + (bg[r] << 3);
        const float a0 = x0[r], a1 = x1[r], a2 = x2c[r], a3 = x3[r];
        const float xq = xs[r];
        int idx = 0x7fffffff;
        #pragma unroll
        for (int h = 0; h < 2; ++h) {
            const float4 sv = sS[(k0 >> 2) + h];
            const float ss[4] = {sv.x, sv.y, sv.z, sv.w};
            #pragma unroll
            for (int j = 0; j < 4; ++j) {
                const int k = k0 + 4 * h + j;
                const float4 e = sE[k];
                float dt = a0 * e.x;
                dt = __builtin_fmaf(a1, e.y, dt);
                dt = __builtin_fmaf(a2, e.z, dt);
                dt = __builtin_fmaf(a3, e.w, dt);
                const float d = (xq + dt) + ss[j];
                idx = min(idx, (d == dmin[r]) ? k : 0x7fffffff);
            }
        }
        // d >= 0 for this data: float bits order-isomorphic as u32; low bits
        // break exact cross-wave ties toward the smaller index.
        key[r] = ((unsigned long long)__float_as_uint(dmin[r]) << 32)
                 | (unsigned)idx;
    }

    // ---- cross-wave reduce: reuse sE's LDS (stride 9 u64 -> 2-way = free) --
    __syncthreads();
    unsigned long long* skey = reinterpret_cast<unsigned long long*>(sE);
    #pragma unroll
    for (int r = 0; r < RPT; ++r)
        skey[(r * 64 + lane) * (KSPLIT + 1) + wid] = key[r];
    __syncthreads();

    if (t < ROWSPB) {
        const int rn = blockIdx.x * ROWSPB + t;
        if (rn < N) {
            unsigned long long k = skey[t * (KSPLIT + 1)];
            #pragma unroll
            for (int s = 1; s < KSPLIT; ++s) {
                unsigned long long v = skey[t * (KSPLIT + 1) + s];
                if (v < k) k = v;
            }
            out[rn] = (int)(unsigned)(k & 0xFFFFFFFFull);
        }
    }
}

extern "C" void kernel_launch(void* const* d_in, const int* in_sizes, int n_in,
                              void* d_out, int out_size, void* d_ws, size_t ws_size,
                              hipStream_t stream) {
    const float* x   = (const float*)d_in[0];   // [16,64,64,4] -> [N,4]
    const float* emb = (const float*)d_in[1];   // [2048,4]
    int* out = (int*)d_out;                     // [N] int32
    const int N = in_sizes[0] / CDIM;           // 65536

    vq_fused<<<(N + ROWSPB - 1) / ROWSPB, 512, 0, stream>>>(x, emb, out, N);
}